// Round 1
// baseline (469.922 us; speedup 1.0000x reference)
//
#include <hip/hip_runtime.h>
#include <cstdint>
#include <cstddef>

// ---------------------------------------------------------------------------
// EfficientAttention: out = ((softmax_N(K)^T V) folded into Wproj) pipeline
//   B=8, N=4096, C=768, H=12, D=64
// Stages:
//   K0a  cast x fp32->bf16                       (Xb)
//   K0b  transpose+cast Wqkv -> WqkvT, Wproj->WpT
//   K1   GEMM1: qkv = Xb @ Wqkv   (m97-style MFMA, epilogue scatters
//          q -> Q[32768,768], k -> KT[96][64][4096], v -> VT[96][64][4096])
//   K3   softmax in place over KT rows (axis = N)
//   K4   ctx partials: per (b,h,kchunk): KT[64,512] @ VT^T -> part fp32
//   K5   Wfused: reduce partials, B2T[b][c'][h*64+d] = sum_e ctx[d,e]*Wp[h*64+e,c']
//   K6   GEMM2: out[b] = Q[b] @ Wfused[b]^T + bproj   (fp32 out)
// ---------------------------------------------------------------------------

typedef __bf16 bf8_t __attribute__((ext_vector_type(8)));
typedef float f4_t __attribute__((ext_vector_type(4)));

#define DEV_INLINE __device__ __forceinline__

DEV_INLINE void gload16(const void* g, void* l) {
  __builtin_amdgcn_global_load_lds(
      (const __attribute__((address_space(1))) void*)g,
      (__attribute__((address_space(3))) void*)l, 16, 0, 0);
}

// ---------------- K0a: cast x (fp32) -> bf16, 4 elems/thread ----------------
__global__ __launch_bounds__(256) void cast_f32_bf16(const float* __restrict__ in,
                                                     __bf16* __restrict__ out, int n4) {
  int i = blockIdx.x * 256 + threadIdx.x;
  if (i >= n4) return;
  float4 f = ((const float4*)in)[i];
  union { __bf16 h[4]; uint2 u; } o;
  o.h[0] = (__bf16)f.x; o.h[1] = (__bf16)f.y; o.h[2] = (__bf16)f.z; o.h[3] = (__bf16)f.w;
  ((uint2*)out)[i] = o.u;
}

// ------------- K0b: out[c*R + r] = (bf16) in[r*C + c]  (transpose) ----------
__global__ __launch_bounds__(256) void transpose_cast(const float* __restrict__ in,
                                                      __bf16* __restrict__ out, int R, int C) {
  int o = blockIdx.x * 256 + threadIdx.x;
  if (o >= R * C) return;
  int c = o / R, r = o - c * R;
  out[o] = (__bf16)in[r * C + c];
}

// ---------------- K1: GEMM1 qkv = Xb @ Wqkv, scatter epilogue ---------------
// A [32768,768] bf16 row-major, B^T = WqkvT [2304,768] bf16 row-major.
// 128x128 tile, BK=32, 256 thr (4 waves, each 64x64 = 4x4 mfma 16x16x32).
__global__ __launch_bounds__(256) void gemm1_qkv(const __bf16* __restrict__ A,
                                                 const __bf16* __restrict__ B,
                                                 __bf16* __restrict__ Qo,
                                                 __bf16* __restrict__ KTo,
                                                 __bf16* __restrict__ VTo) {
  constexpr int LDA = 768, LDB = 768, BK = 32, KTOT = 768, NT = 18;
  __shared__ __bf16 sA[128 * 32];
  __shared__ __bf16 sB[128 * 32];
  const int tid = threadIdx.x;
  const int mt = blockIdx.x / NT, nt = blockIdx.x % NT;
  const int lane = tid & 63, wv = tid >> 6;
  const int wr = (wv >> 1) * 64, wc = (wv & 1) * 64;
  const int lr = lane & 15, quad = lane >> 4;

  const int e0 = tid * 8;            // staging element base (8 bf16 = 16B/lane)
  const int srow = e0 >> 5, skk = e0 & 31;
  const __bf16* gA = A + (size_t)(mt * 128 + srow) * LDA + skk;
  const __bf16* gB = B + (size_t)(nt * 128 + srow) * LDB + skk;

  const f4_t fz = {0.f, 0.f, 0.f, 0.f};
  f4_t acc[4][4];
#pragma unroll
  for (int i = 0; i < 4; i++)
#pragma unroll
    for (int j = 0; j < 4; j++) acc[i][j] = fz;

  for (int k0 = 0; k0 < KTOT; k0 += BK) {
    gload16(gA, &sA[e0]);
    gload16(gA + 64 * LDA, &sA[e0 + 2048]);
    gload16(gB, &sB[e0]);
    gload16(gB + 64 * LDB, &sB[e0 + 2048]);
    gA += BK; gB += BK;
    __syncthreads();
    bf8_t af[4], bfm[4];
#pragma unroll
    for (int i = 0; i < 4; i++)
      af[i] = *(const bf8_t*)&sA[(wr + i * 16 + lr) * 32 + quad * 8];
#pragma unroll
    for (int j = 0; j < 4; j++)
      bfm[j] = *(const bf8_t*)&sB[(wc + j * 16 + lr) * 32 + quad * 8];
#pragma unroll
    for (int i = 0; i < 4; i++)
#pragma unroll
      for (int j = 0; j < 4; j++)
        acc[i][j] = __builtin_amdgcn_mfma_f32_16x16x32_bf16(af[i], bfm[j], acc[i][j], 0, 0, 0);
    __syncthreads();
  }

  // epilogue: C/D layout col = lane&15, row = quad*4 + r
  const int s = nt / 6;                 // 0=q, 1=k, 2=v (tiles align: 768/128=6)
  const int colw0 = (nt % 6) * 128 + wc;
  const int row0 = mt * 128 + wr;
  if (s == 0) {
#pragma unroll
    for (int i = 0; i < 4; i++)
#pragma unroll
      for (int j = 0; j < 4; j++) {
        int col = colw0 + j * 16 + lr;
#pragma unroll
        for (int r = 0; r < 4; r++)
          Qo[(size_t)(row0 + i * 16 + quad * 4 + r) * 768 + col] = (__bf16)acc[i][j][r];
      }
  } else {
    __bf16* T = (s == 1) ? KTo : VTo;
    const int b = row0 >> 12;           // 128-row tile never crosses batch
    const int n0 = (row0 & 4095) + quad * 4;
#pragma unroll
    for (int i = 0; i < 4; i++) {
      int n = n0 + i * 16;
#pragma unroll
      for (int j = 0; j < 4; j++) {
        int cw = colw0 + j * 16 + lr;
        int h = cw >> 6, d = cw & 63;
        union { __bf16 h4[4]; uint2 u; } pk;
#pragma unroll
        for (int r = 0; r < 4; r++) pk.h4[r] = (__bf16)acc[i][j][r];
        *(uint2*)&T[((size_t)(b * 12 + h) * 64 + d) * 4096 + n] = pk.u;
      }
    }
  }
}

// ---------------- K3: softmax over each KT row (4096, contiguous) -----------
__global__ __launch_bounds__(256) void softmax_rows(__bf16* __restrict__ KT) {
  __shared__ float red[8];
  __bf16* p = KT + (size_t)blockIdx.x * 4096;
  const int tid = threadIdx.x, lane = tid & 63, wv = tid >> 6;
  bf8_t x0 = *(const bf8_t*)&p[tid * 16];
  bf8_t x1 = *(const bf8_t*)&p[tid * 16 + 8];
  float v[16];
#pragma unroll
  for (int k = 0; k < 8; k++) { v[k] = (float)x0[k]; v[8 + k] = (float)x1[k]; }
  float m = v[0];
#pragma unroll
  for (int k = 1; k < 16; k++) m = fmaxf(m, v[k]);
  for (int o = 32; o; o >>= 1) m = fmaxf(m, __shfl_xor(m, o, 64));
  if (lane == 0) red[wv] = m;
  __syncthreads();
  m = fmaxf(fmaxf(red[0], red[1]), fmaxf(red[2], red[3]));
  float s = 0.f;
#pragma unroll
  for (int k = 0; k < 16; k++) { v[k] = __expf(v[k] - m); s += v[k]; }
  for (int o = 32; o; o >>= 1) s += __shfl_xor(s, o, 64);
  if (lane == 0) red[4 + wv] = s;
  __syncthreads();
  s = red[4] + red[5] + red[6] + red[7];
  float inv = 1.0f / s;
  bf8_t o0, o1;
#pragma unroll
  for (int k = 0; k < 8; k++) { o0[k] = (__bf16)(v[k] * inv); o1[k] = (__bf16)(v[8 + k] * inv); }
  *(bf8_t*)&p[tid * 16] = o0;
  *(bf8_t*)&p[tid * 16 + 8] = o1;
}

// --------- K4: ctx partials. grid = 96*8; block (b,h,kc): K-slice 512 -------
// part[(bh*8+kc)][d][e] = sum_{n in slice} KT[bh][d][n] * VT[bh][e][n]
__global__ __launch_bounds__(256) void ctx_kernel(const __bf16* __restrict__ KT,
                                                  const __bf16* __restrict__ VT,
                                                  float* __restrict__ part) {
  const int bh = blockIdx.x >> 3, kc = blockIdx.x & 7;
  const int tid = threadIdx.x, lane = tid & 63, wv = tid >> 6;
  const int wr = (wv >> 1) * 32, wc = (wv & 1) * 32;
  const int lr = lane & 15, quad = lane >> 4;
  const __bf16* Ab = KT + (size_t)bh * 64 * 4096;
  const __bf16* Bb = VT + (size_t)bh * 64 * 4096;
  const f4_t fz = {0.f, 0.f, 0.f, 0.f};
  f4_t acc[2][2] = {{fz, fz}, {fz, fz}};
  const int kbeg = kc * 512;
  for (int k0 = kbeg; k0 < kbeg + 512; k0 += 32) {
    bf8_t a[2], b[2];
#pragma unroll
    for (int i = 0; i < 2; i++)
      a[i] = *(const bf8_t*)&Ab[(size_t)(wr + i * 16 + lr) * 4096 + k0 + quad * 8];
#pragma unroll
    for (int j = 0; j < 2; j++)
      b[j] = *(const bf8_t*)&Bb[(size_t)(wc + j * 16 + lr) * 4096 + k0 + quad * 8];
#pragma unroll
    for (int i = 0; i < 2; i++)
#pragma unroll
      for (int j = 0; j < 2; j++)
        acc[i][j] = __builtin_amdgcn_mfma_f32_16x16x32_bf16(a[i], b[j], acc[i][j], 0, 0, 0);
  }
  float* po = part + (size_t)blockIdx.x * 4096;
#pragma unroll
  for (int i = 0; i < 2; i++)
#pragma unroll
    for (int j = 0; j < 2; j++)
#pragma unroll
      for (int r = 0; r < 4; r++)
        po[(wr + i * 16 + quad * 4 + r) * 64 + wc + j * 16 + lr] = acc[i][j][r];
}

// -------- K5: B2T[b][c][h*64+d] = sum_e ctx[bh][d][e] * Wproj[h*64+e][c] ----
// grid (96, 4): bh, c-block of 192. A = WpT (Wproj^T bf16), B^T = ctx (LDS).
__global__ __launch_bounds__(256) void wfused_kernel(const float* __restrict__ part,
                                                     const __bf16* __restrict__ WpT,
                                                     __bf16* __restrict__ B2T) {
  __shared__ __bf16 sctx[64 * 64];
  const int bh = blockIdx.x, cblk = blockIdx.y;
  const int b = bh / 12, h = bh % 12;
  const int tid = threadIdx.x;
  for (int i = tid; i < 4096; i += 256) {
    float s = 0.f;
#pragma unroll
    for (int kc = 0; kc < 8; kc++) s += part[(size_t)(bh * 8 + kc) * 4096 + i];
    sctx[i] = (__bf16)s;
  }
  __syncthreads();
  const int lane = tid & 63, wv = tid >> 6, lr = lane & 15, quad = lane >> 4;
  const int c0 = cblk * 192 + wv * 48;
  const f4_t fz = {0.f, 0.f, 0.f, 0.f};
  f4_t acc[3][4];
#pragma unroll
  for (int i = 0; i < 3; i++)
#pragma unroll
    for (int j = 0; j < 4; j++) acc[i][j] = fz;
#pragma unroll
  for (int k0 = 0; k0 < 64; k0 += 32) {
    bf8_t a[3], bq[4];
#pragma unroll
    for (int i = 0; i < 3; i++)
      a[i] = *(const bf8_t*)&WpT[(size_t)(c0 + i * 16 + lr) * 768 + h * 64 + k0 + quad * 8];
#pragma unroll
    for (int j = 0; j < 4; j++)
      bq[j] = *(const bf8_t*)&sctx[(j * 16 + lr) * 64 + k0 + quad * 8];
#pragma unroll
    for (int i = 0; i < 3; i++)
#pragma unroll
      for (int j = 0; j < 4; j++)
        acc[i][j] = __builtin_amdgcn_mfma_f32_16x16x32_bf16(a[i], bq[j], acc[i][j], 0, 0, 0);
  }
#pragma unroll
  for (int i = 0; i < 3; i++)
#pragma unroll
    for (int j = 0; j < 4; j++)
#pragma unroll
      for (int r = 0; r < 4; r++) {
        int c = c0 + i * 16 + quad * 4 + r;
        int d = j * 16 + lr;
        B2T[((size_t)b * 768 + c) * 768 + h * 64 + d] = (__bf16)acc[i][j][r];
      }
}

// ------------- K6: GEMM2 out = Q @ B2T[b]^T + bproj (fp32 out) --------------
__global__ __launch_bounds__(256) void gemm2_out(const __bf16* __restrict__ A,
                                                 const __bf16* __restrict__ Ball,
                                                 float* __restrict__ C,
                                                 const float* __restrict__ bias) {
  constexpr int LDA = 768, LDB = 768, BK = 32, KTOT = 768, NT = 6;
  __shared__ __bf16 sA[128 * 32];
  __shared__ __bf16 sB[128 * 32];
  const int tid = threadIdx.x;
  const int mt = blockIdx.x / NT, nt = blockIdx.x % NT;
  const __bf16* B = Ball + (size_t)(mt >> 5) * 768 * 768;  // batch = row-tile/32
  const int lane = tid & 63, wv = tid >> 6;
  const int wr = (wv >> 1) * 64, wc = (wv & 1) * 64;
  const int lr = lane & 15, quad = lane >> 4;

  const int e0 = tid * 8;
  const int srow = e0 >> 5, skk = e0 & 31;
  const __bf16* gA = A + (size_t)(mt * 128 + srow) * LDA + skk;
  const __bf16* gB = B + (size_t)(nt * 128 + srow) * LDB + skk;

  const f4_t fz = {0.f, 0.f, 0.f, 0.f};
  f4_t acc[4][4];
#pragma unroll
  for (int i = 0; i < 4; i++)
#pragma unroll
    for (int j = 0; j < 4; j++) acc[i][j] = fz;

  for (int k0 = 0; k0 < KTOT; k0 += BK) {
    gload16(gA, &sA[e0]);
    gload16(gA + 64 * LDA, &sA[e0 + 2048]);
    gload16(gB, &sB[e0]);
    gload16(gB + 64 * LDB, &sB[e0 + 2048]);
    gA += BK; gB += BK;
    __syncthreads();
    bf8_t af[4], bfm[4];
#pragma unroll
    for (int i = 0; i < 4; i++)
      af[i] = *(const bf8_t*)&sA[(wr + i * 16 + lr) * 32 + quad * 8];
#pragma unroll
    for (int j = 0; j < 4; j++)
      bfm[j] = *(const bf8_t*)&sB[(wc + j * 16 + lr) * 32 + quad * 8];
#pragma unroll
    for (int i = 0; i < 4; i++)
#pragma unroll
      for (int j = 0; j < 4; j++)
        acc[i][j] = __builtin_amdgcn_mfma_f32_16x16x32_bf16(af[i], bfm[j], acc[i][j], 0, 0, 0);
    __syncthreads();
  }

  const int row0 = mt * 128 + wr;
  const int col0 = nt * 128 + wc;
#pragma unroll
  for (int j = 0; j < 4; j++) {
    int col = col0 + j * 16 + lr;
    float bv = bias[col];
#pragma unroll
    for (int i = 0; i < 4; i++)
#pragma unroll
      for (int r = 0; r < 4; r++)
        C[(size_t)(row0 + i * 16 + quad * 4 + r) * 768 + col] = acc[i][j][r] + bv;
  }
}

// ---------------------------------------------------------------------------
extern "C" void kernel_launch(void* const* d_in, const int* in_sizes, int n_in,
                              void* d_out, int out_size, void* d_ws, size_t ws_size,
                              hipStream_t stream) {
  const float* x = (const float*)d_in[0];      // [8,4096,768]
  const float* Wqkv = (const float*)d_in[1];   // [768,2304]
  const float* Wproj = (const float*)d_in[2];  // [768,768]
  const float* bproj = (const float*)d_in[3];  // [768]
  float* out = (float*)d_out;                  // [8,4096,768]

  char* ws = (char*)d_ws;
  // Xb occupies [0, 50331648); part/B2T alias it (Xb dead after GEMM1... K4/K5/K6)
  __bf16* Xb   = (__bf16*)(ws + 0);
  float*  part = (float*)(ws + 0);              // 96*8*4096*4 = 12,582,912
  __bf16* B2T  = (__bf16*)(ws + 12582912);      // 8*768*768*2 =  9,437,184
  __bf16* WqkvT = (__bf16*)(ws + 50331648);     // 2304*768*2  =  3,538,944
  __bf16* WpT   = (__bf16*)(ws + 53870592);     // 768*768*2   =  1,179,648
  __bf16* Q     = (__bf16*)(ws + 55050240);     // 32768*768*2 = 50,331,648
  __bf16* KT    = (__bf16*)(ws + 105381888);    // 96*64*4096*2= 50,331,648
  __bf16* VT    = (__bf16*)(ws + 155713536);    // 50,331,648  -> end 206,045,184

  cast_f32_bf16<<<24576, 256, 0, stream>>>(x, Xb, 25165824 / 4);
  transpose_cast<<<(768 * 2304) / 256, 256, 0, stream>>>(Wqkv, WqkvT, 768, 2304);
  transpose_cast<<<(768 * 768) / 256, 256, 0, stream>>>(Wproj, WpT, 768, 768);
  gemm1_qkv<<<256 * 18, 256, 0, stream>>>(Xb, WqkvT, Q, KT, VT);
  softmax_rows<<<6144, 256, 0, stream>>>(KT);
  ctx_kernel<<<96 * 8, 256, 0, stream>>>(KT, VT, part);
  wfused_kernel<<<dim3(96, 4), 256, 0, stream>>>(part, WpT, B2T);
  gemm2_out<<<256 * 6, 256, 0, stream>>>(Q, B2T, out, bproj);
}

// Round 2
// 450.613 us; speedup vs baseline: 1.0429x; 1.0429x over previous
//
#include <hip/hip_runtime.h>
#include <cstdint>
#include <cstddef>

// ---------------------------------------------------------------------------
// EfficientAttention, Q-folded pipeline:
//   out = x @ (Wq @ Wfused[b]) + bias, where Wfused[b] = ctx[b] folded into Wproj
// Stages:
//   K0a  cast x fp32->bf16                        (Xb)
//   K0b  transpose+cast Wqkv -> WqkvT, Wproj -> WpT; cast Wq (no transpose)
//   K1   GEMM1: kv = Xb @ Wqkv[:,768:]  (epilogue scatters
//          k -> KT[96][64][4096], v -> VT[96][64][4096])
//   K3   softmax in place over KT rows (axis = N)
//   K4   ctx partials: per (b,h,kchunk): KT[64,512] @ VT^T -> part fp32
//   K5   Wfused: reduce partials, B2T[b][c'][h*64+d] = sum_e ctx[d,e]*Wp[h*64+e,c']
//   K5b  combine: Wcomb^T[b] = B2T[b] @ Wq^T   (bf16, [c_out][c_in])
//   K6   GEMM2: out[b] = Xb[b] @ Wcomb[b] + bproj   (fp32 out)
// ---------------------------------------------------------------------------

typedef __bf16 bf8_t __attribute__((ext_vector_type(8)));
typedef float f4_t __attribute__((ext_vector_type(4)));

#define DEV_INLINE __device__ __forceinline__

DEV_INLINE void gload16(const void* g, void* l) {
  __builtin_amdgcn_global_load_lds(
      (const __attribute__((address_space(1))) void*)g,
      (__attribute__((address_space(3))) void*)l, 16, 0, 0);
}

// ---------------- K0a: cast x (fp32) -> bf16, 4 elems/thread ----------------
__global__ __launch_bounds__(256) void cast_f32_bf16(const float* __restrict__ in,
                                                     __bf16* __restrict__ out, int n4) {
  int i = blockIdx.x * 256 + threadIdx.x;
  if (i >= n4) return;
  float4 f = ((const float4*)in)[i];
  union { __bf16 h[4]; uint2 u; } o;
  o.h[0] = (__bf16)f.x; o.h[1] = (__bf16)f.y; o.h[2] = (__bf16)f.z; o.h[3] = (__bf16)f.w;
  ((uint2*)out)[i] = o.u;
}

// ------------- K0b: out[c*R + r] = (bf16) in[r*C + c]  (transpose) ----------
__global__ __launch_bounds__(256) void transpose_cast(const float* __restrict__ in,
                                                      __bf16* __restrict__ out, int R, int C) {
  int o = blockIdx.x * 256 + threadIdx.x;
  if (o >= R * C) return;
  int c = o / R, r = o - c * R;
  out[o] = (__bf16)in[r * C + c];
}

// ---- K0c: Wq_cast[r][k] = (bf16) Wqkv[r][k], k<768 (strided row cast) ------
__global__ __launch_bounds__(256) void wq_cast(const float* __restrict__ in,
                                               __bf16* __restrict__ out) {
  int o = blockIdx.x * 256 + threadIdx.x;   // o in [0, 768*768)
  int r = o / 768, c = o - r * 768;
  out[o] = (__bf16)in[r * 2304 + c];
}

// ---------------- K1: GEMM1 kv = Xb @ Wqkv[:,768:], scatter epilogue --------
// A [32768,768] bf16 row-major, B^T = WqkvT rows 768..2303 [1536,768].
// 128x128 tile, BK=32, 256 thr (4 waves, each 64x64 = 4x4 mfma 16x16x32).
__global__ __launch_bounds__(256) void gemm1_kv(const __bf16* __restrict__ A,
                                                const __bf16* __restrict__ B,
                                                __bf16* __restrict__ KTo,
                                                __bf16* __restrict__ VTo) {
  constexpr int LDA = 768, LDB = 768, BK = 32, KTOT = 768, NT = 12;
  __shared__ __bf16 sA[128 * 32];
  __shared__ __bf16 sB[128 * 32];
  const int tid = threadIdx.x;
  const int mt = blockIdx.x / NT, nt = blockIdx.x % NT;
  const int lane = tid & 63, wv = tid >> 6;
  const int wr = (wv >> 1) * 64, wc = (wv & 1) * 64;
  const int lr = lane & 15, quad = lane >> 4;

  const int e0 = tid * 8;            // staging element base (8 bf16 = 16B/lane)
  const int srow = e0 >> 5, skk = e0 & 31;
  const __bf16* gA = A + (size_t)(mt * 128 + srow) * LDA + skk;
  const __bf16* gB = B + (size_t)(nt * 128 + srow) * LDB + skk;

  const f4_t fz = {0.f, 0.f, 0.f, 0.f};
  f4_t acc[4][4];
#pragma unroll
  for (int i = 0; i < 4; i++)
#pragma unroll
    for (int j = 0; j < 4; j++) acc[i][j] = fz;

  for (int k0 = 0; k0 < KTOT; k0 += BK) {
    gload16(gA, &sA[e0]);
    gload16(gA + 64 * LDA, &sA[e0 + 2048]);
    gload16(gB, &sB[e0]);
    gload16(gB + 64 * LDB, &sB[e0 + 2048]);
    gA += BK; gB += BK;
    __syncthreads();
    bf8_t af[4], bfm[4];
#pragma unroll
    for (int i = 0; i < 4; i++)
      af[i] = *(const bf8_t*)&sA[(wr + i * 16 + lr) * 32 + quad * 8];
#pragma unroll
    for (int j = 0; j < 4; j++)
      bfm[j] = *(const bf8_t*)&sB[(wc + j * 16 + lr) * 32 + quad * 8];
#pragma unroll
    for (int i = 0; i < 4; i++)
#pragma unroll
      for (int j = 0; j < 4; j++)
        acc[i][j] = __builtin_amdgcn_mfma_f32_16x16x32_bf16(af[i], bfm[j], acc[i][j], 0, 0, 0);
    __syncthreads();
  }

  // epilogue: C/D layout col = lane&15, row = quad*4 + r; nt 0..5 = k, 6..11 = v
  const int s = nt / 6;
  const int colw0 = (nt % 6) * 128 + wc;
  const int row0 = mt * 128 + wr;
  __bf16* T = (s == 0) ? KTo : VTo;
  const int b = row0 >> 12;           // 128-row tile never crosses batch
  const int n0 = (row0 & 4095) + quad * 4;
#pragma unroll
  for (int i = 0; i < 4; i++) {
    int n = n0 + i * 16;
#pragma unroll
    for (int j = 0; j < 4; j++) {
      int cw = colw0 + j * 16 + lr;
      int h = cw >> 6, d = cw & 63;
      union { __bf16 h4[4]; uint2 u; } pk;
#pragma unroll
      for (int r = 0; r < 4; r++) pk.h4[r] = (__bf16)acc[i][j][r];
      *(uint2*)&T[((size_t)(b * 12 + h) * 64 + d) * 4096 + n] = pk.u;
    }
  }
}

// ---------------- K3: softmax over each KT row (4096, contiguous) -----------
__global__ __launch_bounds__(256) void softmax_rows(__bf16* __restrict__ KT) {
  __shared__ float red[8];
  __bf16* p = KT + (size_t)blockIdx.x * 4096;
  const int tid = threadIdx.x, lane = tid & 63, wv = tid >> 6;
  bf8_t x0 = *(const bf8_t*)&p[tid * 16];
  bf8_t x1 = *(const bf8_t*)&p[tid * 16 + 8];
  float v[16];
#pragma unroll
  for (int k = 0; k < 8; k++) { v[k] = (float)x0[k]; v[8 + k] = (float)x1[k]; }
  float m = v[0];
#pragma unroll
  for (int k = 1; k < 16; k++) m = fmaxf(m, v[k]);
  for (int o = 32; o; o >>= 1) m = fmaxf(m, __shfl_xor(m, o, 64));
  if (lane == 0) red[wv] = m;
  __syncthreads();
  m = fmaxf(fmaxf(red[0], red[1]), fmaxf(red[2], red[3]));
  float s = 0.f;
#pragma unroll
  for (int k = 0; k < 16; k++) { v[k] = __expf(v[k] - m); s += v[k]; }
  for (int o = 32; o; o >>= 1) s += __shfl_xor(s, o, 64);
  if (lane == 0) red[4 + wv] = s;
  __syncthreads();
  s = red[4] + red[5] + red[6] + red[7];
  float inv = 1.0f / s;
  bf8_t o0, o1;
#pragma unroll
  for (int k = 0; k < 8; k++) { o0[k] = (__bf16)(v[k] * inv); o1[k] = (__bf16)(v[8 + k] * inv); }
  *(bf8_t*)&p[tid * 16] = o0;
  *(bf8_t*)&p[tid * 16 + 8] = o1;
}

// --------- K4: ctx partials. grid = 96*8; block (b,h,kc): K-slice 512 -------
// part[(bh*8+kc)][d][e] = sum_{n in slice} KT[bh][d][n] * VT[bh][e][n]
__global__ __launch_bounds__(256) void ctx_kernel(const __bf16* __restrict__ KT,
                                                  const __bf16* __restrict__ VT,
                                                  float* __restrict__ part) {
  const int bh = blockIdx.x >> 3, kc = blockIdx.x & 7;
  const int tid = threadIdx.x, lane = tid & 63, wv = tid >> 6;
  const int wr = (wv >> 1) * 32, wc = (wv & 1) * 32;
  const int lr = lane & 15, quad = lane >> 4;
  const __bf16* Ab = KT + (size_t)bh * 64 * 4096;
  const __bf16* Bb = VT + (size_t)bh * 64 * 4096;
  const f4_t fz = {0.f, 0.f, 0.f, 0.f};
  f4_t acc[2][2] = {{fz, fz}, {fz, fz}};
  const int kbeg = kc * 512;
  for (int k0 = kbeg; k0 < kbeg + 512; k0 += 32) {
    bf8_t a[2], b[2];
#pragma unroll
    for (int i = 0; i < 2; i++)
      a[i] = *(const bf8_t*)&Ab[(size_t)(wr + i * 16 + lr) * 4096 + k0 + quad * 8];
#pragma unroll
    for (int j = 0; j < 2; j++)
      b[j] = *(const bf8_t*)&Bb[(size_t)(wc + j * 16 + lr) * 4096 + k0 + quad * 8];
#pragma unroll
    for (int i = 0; i < 2; i++)
#pragma unroll
      for (int j = 0; j < 2; j++)
        acc[i][j] = __builtin_amdgcn_mfma_f32_16x16x32_bf16(a[i], b[j], acc[i][j], 0, 0, 0);
  }
  float* po = part + (size_t)blockIdx.x * 4096;
#pragma unroll
  for (int i = 0; i < 2; i++)
#pragma unroll
    for (int j = 0; j < 2; j++)
#pragma unroll
      for (int r = 0; r < 4; r++)
        po[(wr + i * 16 + quad * 4 + r) * 64 + wc + j * 16 + lr] = acc[i][j][r];
}

// -------- K5: B2T[b][c][h*64+d] = sum_e ctx[bh][d][e] * Wproj[h*64+e][c] ----
// grid (96, 4): bh, c-block of 192. A = WpT (Wproj^T bf16), B^T = ctx (LDS).
__global__ __launch_bounds__(256) void wfused_kernel(const float* __restrict__ part,
                                                     const __bf16* __restrict__ WpT,
                                                     __bf16* __restrict__ B2T) {
  __shared__ __bf16 sctx[64 * 64];
  const int bh = blockIdx.x, cblk = blockIdx.y;
  const int b = bh / 12, h = bh % 12;
  const int tid = threadIdx.x;
  for (int i = tid; i < 4096; i += 256) {
    float s = 0.f;
#pragma unroll
    for (int kc = 0; kc < 8; kc++) s += part[(size_t)(bh * 8 + kc) * 4096 + i];
    sctx[i] = (__bf16)s;
  }
  __syncthreads();
  const int lane = tid & 63, wv = tid >> 6, lr = lane & 15, quad = lane >> 4;
  const int c0 = cblk * 192 + wv * 48;
  const f4_t fz = {0.f, 0.f, 0.f, 0.f};
  f4_t acc[3][4];
#pragma unroll
  for (int i = 0; i < 3; i++)
#pragma unroll
    for (int j = 0; j < 4; j++) acc[i][j] = fz;
#pragma unroll
  for (int k0 = 0; k0 < 64; k0 += 32) {
    bf8_t a[3], bq[4];
#pragma unroll
    for (int i = 0; i < 3; i++)
      a[i] = *(const bf8_t*)&WpT[(size_t)(c0 + i * 16 + lr) * 768 + h * 64 + k0 + quad * 8];
#pragma unroll
    for (int j = 0; j < 4; j++)
      bq[j] = *(const bf8_t*)&sctx[(j * 16 + lr) * 64 + k0 + quad * 8];
#pragma unroll
    for (int i = 0; i < 3; i++)
#pragma unroll
      for (int j = 0; j < 4; j++)
        acc[i][j] = __builtin_amdgcn_mfma_f32_16x16x32_bf16(a[i], bq[j], acc[i][j], 0, 0, 0);
  }
#pragma unroll
  for (int i = 0; i < 3; i++)
#pragma unroll
    for (int j = 0; j < 4; j++)
#pragma unroll
      for (int r = 0; r < 4; r++) {
        int c = c0 + i * 16 + quad * 4 + r;
        int d = j * 16 + lr;
        B2T[((size_t)b * 768 + c) * 768 + h * 64 + d] = (__bf16)acc[i][j][r];
      }
}

// ------ K5b: combine  Wcomb^T[b][c_out][c_in] = sum_k B2T[b][c_out][k]*Wq[c_in][k]
// 64x64 tiles for occupancy: grid = 8 * 12 * 12 = 1152 blocks.
__global__ __launch_bounds__(256) void combine_kernel(const __bf16* __restrict__ B2Tall,
                                                      const __bf16* __restrict__ Wq,
                                                      __bf16* __restrict__ Wcomb) {
  constexpr int LD = 768, BK = 32, KTOT = 768;
  __shared__ __bf16 sA[64 * 32];
  __shared__ __bf16 sB[64 * 32];
  const int b = blockIdx.x / 144, rem = blockIdx.x % 144;
  const int mt = rem / 12, nt = rem % 12;
  const __bf16* A = B2Tall + (size_t)b * 768 * 768;
  const int tid = threadIdx.x, lane = tid & 63, wv = tid >> 6;
  const int wr = (wv >> 1) * 32, wc = (wv & 1) * 32;
  const int lr = lane & 15, quad = lane >> 4;

  const int e0 = tid * 8;            // 256 lanes * 16B = 4096B = full 64x32 tile
  const int srow = e0 >> 5, skk = e0 & 31;
  const __bf16* gA = A + (size_t)(mt * 64 + srow) * LD + skk;
  const __bf16* gB = Wq + (size_t)(nt * 64 + srow) * LD + skk;

  const f4_t fz = {0.f, 0.f, 0.f, 0.f};
  f4_t acc[2][2] = {{fz, fz}, {fz, fz}};

  for (int k0 = 0; k0 < KTOT; k0 += BK) {
    gload16(gA, &sA[e0]);
    gload16(gB, &sB[e0]);
    gA += BK; gB += BK;
    __syncthreads();
    bf8_t a[2], bq[2];
#pragma unroll
    for (int i = 0; i < 2; i++)
      a[i] = *(const bf8_t*)&sA[(wr + i * 16 + lr) * 32 + quad * 8];
#pragma unroll
    for (int j = 0; j < 2; j++)
      bq[j] = *(const bf8_t*)&sB[(wc + j * 16 + lr) * 32 + quad * 8];
#pragma unroll
    for (int i = 0; i < 2; i++)
#pragma unroll
      for (int j = 0; j < 2; j++)
        acc[i][j] = __builtin_amdgcn_mfma_f32_16x16x32_bf16(a[i], bq[j], acc[i][j], 0, 0, 0);
    __syncthreads();
  }
  __bf16* C = Wcomb + (size_t)b * 768 * 768;
  const int row0 = mt * 64 + wr, col0 = nt * 64 + wc;
#pragma unroll
  for (int i = 0; i < 2; i++)
#pragma unroll
    for (int j = 0; j < 2; j++)
#pragma unroll
      for (int r = 0; r < 4; r++)
        C[(size_t)(row0 + i * 16 + quad * 4 + r) * 768 + col0 + j * 16 + lr] =
            (__bf16)acc[i][j][r];
}

// ------------- K6: GEMM2 out = Xb @ Wcomb^T[b] + bproj (fp32 out) -----------
__global__ __launch_bounds__(256) void gemm2_out(const __bf16* __restrict__ A,
                                                 const __bf16* __restrict__ Ball,
                                                 float* __restrict__ C,
                                                 const float* __restrict__ bias) {
  constexpr int LDA = 768, LDB = 768, BK = 32, KTOT = 768, NT = 6;
  __shared__ __bf16 sA[128 * 32];
  __shared__ __bf16 sB[128 * 32];
  const int tid = threadIdx.x;
  const int mt = blockIdx.x / NT, nt = blockIdx.x % NT;
  const __bf16* B = Ball + (size_t)(mt >> 5) * 768 * 768;  // batch = row-tile/32
  const int lane = tid & 63, wv = tid >> 6;
  const int wr = (wv >> 1) * 64, wc = (wv & 1) * 64;
  const int lr = lane & 15, quad = lane >> 4;

  const int e0 = tid * 8;
  const int srow = e0 >> 5, skk = e0 & 31;
  const __bf16* gA = A + (size_t)(mt * 128 + srow) * LDA + skk;
  const __bf16* gB = B + (size_t)(nt * 128 + srow) * LDB + skk;

  const f4_t fz = {0.f, 0.f, 0.f, 0.f};
  f4_t acc[4][4];
#pragma unroll
  for (int i = 0; i < 4; i++)
#pragma unroll
    for (int j = 0; j < 4; j++) acc[i][j] = fz;

  for (int k0 = 0; k0 < KTOT; k0 += BK) {
    gload16(gA, &sA[e0]);
    gload16(gA + 64 * LDA, &sA[e0 + 2048]);
    gload16(gB, &sB[e0]);
    gload16(gB + 64 * LDB, &sB[e0 + 2048]);
    gA += BK; gB += BK;
    __syncthreads();
    bf8_t af[4], bfm[4];
#pragma unroll
    for (int i = 0; i < 4; i++)
      af[i] = *(const bf8_t*)&sA[(wr + i * 16 + lr) * 32 + quad * 8];
#pragma unroll
    for (int j = 0; j < 4; j++)
      bfm[j] = *(const bf8_t*)&sB[(wc + j * 16 + lr) * 32 + quad * 8];
#pragma unroll
    for (int i = 0; i < 4; i++)
#pragma unroll
      for (int j = 0; j < 4; j++)
        acc[i][j] = __builtin_amdgcn_mfma_f32_16x16x32_bf16(af[i], bfm[j], acc[i][j], 0, 0, 0);
    __syncthreads();
  }

  const int row0 = mt * 128 + wr;
  const int col0 = nt * 128 + wc;
#pragma unroll
  for (int j = 0; j < 4; j++) {
    int col = col0 + j * 16 + lr;
    float bv = bias[col];
#pragma unroll
    for (int i = 0; i < 4; i++)
#pragma unroll
      for (int r = 0; r < 4; r++)
        C[(size_t)(row0 + i * 16 + quad * 4 + r) * 768 + col] = acc[i][j][r] + bv;
  }
}

// ---------------------------------------------------------------------------
extern "C" void kernel_launch(void* const* d_in, const int* in_sizes, int n_in,
                              void* d_out, int out_size, void* d_ws, size_t ws_size,
                              hipStream_t stream) {
  const float* x = (const float*)d_in[0];      // [8,4096,768]
  const float* Wqkv = (const float*)d_in[1];   // [768,2304]
  const float* Wproj = (const float*)d_in[2];  // [768,768]
  const float* bproj = (const float*)d_in[3];  // [768]
  float* out = (float*)d_out;                  // [8,4096,768]

  char* ws = (char*)d_ws;
  __bf16* Xb    = (__bf16*)(ws + 0);            // 50,331,648
  __bf16* KT    = (__bf16*)(ws + 50331648);     // 50,331,648
  __bf16* VT    = (__bf16*)(ws + 100663296);    // 50,331,648
  __bf16* WqkvT = (__bf16*)(ws + 150994944);    //  3,538,944
  __bf16* Wqc   = (__bf16*)(ws + 154533888);    //  1,179,648
  __bf16* WpT   = (__bf16*)(ws + 155713536);    //  1,179,648
  float*  part  = (float*)(ws + 156893184);     // 12,582,912
  __bf16* B2T   = (__bf16*)(ws + 169476096);    //  9,437,184
  __bf16* Wcomb = (__bf16*)(ws + 178913280);    //  9,437,184 -> end 188,350,464

  cast_f32_bf16<<<24576, 256, 0, stream>>>(x, Xb, 25165824 / 4);
  transpose_cast<<<(768 * 2304) / 256, 256, 0, stream>>>(Wqkv, WqkvT, 768, 2304);
  wq_cast<<<(768 * 768) / 256, 256, 0, stream>>>(Wqkv, Wqc);
  transpose_cast<<<(768 * 768) / 256, 256, 0, stream>>>(Wproj, WpT, 768, 768);
  gemm1_kv<<<256 * 12, 256, 0, stream>>>(Xb, WqkvT + 768 * 768, KT, VT);
  softmax_rows<<<6144, 256, 0, stream>>>(KT);
  ctx_kernel<<<96 * 8, 256, 0, stream>>>(KT, VT, part);
  wfused_kernel<<<dim3(96, 4), 256, 0, stream>>>(part, WpT, B2T);
  combine_kernel<<<1152, 256, 0, stream>>>(B2T, Wqc, Wcomb);
  gemm2_out<<<256 * 6, 256, 0, stream>>>(Xb, Wcomb, out, bproj);
}

// Round 3
// 422.141 us; speedup vs baseline: 1.1132x; 1.0674x over previous
//
#include <hip/hip_runtime.h>
#include <cstdint>
#include <cstddef>

// ---------------------------------------------------------------------------
// EfficientAttention, Q-folded pipeline (Round 3):
//   out = x @ (Wq @ Wfused[b]) + bias
// Stages:
//   K0a  cast x fp32->bf16                        (Xb)
//   K0b  tiled transpose+cast Wqkv -> WqkvT, Wproj -> WpT; cast Wq
//   K1   GEMM1 (32x32x16 MFMA, swizzled LDS): kv = Xb @ Wqkv[:,768:]
//          epilogue scatters k -> KT[96][64][4096], v -> VT[96][64][4096]
//   K3   stats: per KT row (bh,d): m = max_n, inv = 1/sum exp(k-m)  (no writeback)
//   K4   ctx partials: exp applied inline; KT,VT -> part fp32
//   K5   wfused: B2T[b][c'][h*64+d] = sum_e ctx[d,e]*Wproj[h*64+e,c']
//   K5b  combine: Wcomb^T[b] = B2T[b] @ Wq^T
//   K6   GEMM2 (32x32x16, swizzled): out[b] = Xb[b] @ Wcomb[b]^T + bproj
// ---------------------------------------------------------------------------

typedef __bf16 bf8_t __attribute__((ext_vector_type(8)));
typedef float f4_t __attribute__((ext_vector_type(4)));
typedef float f16_t __attribute__((ext_vector_type(16)));

#define DEV_INLINE __device__ __forceinline__

DEV_INLINE void gload16(const void* g, void* l) {
  __builtin_amdgcn_global_load_lds(
      (const __attribute__((address_space(1))) void*)g,
      (__attribute__((address_space(3))) void*)l, 16, 0, 0);
}

// ---------------- K0a: cast x (fp32) -> bf16, 4 elems/thread ----------------
__global__ __launch_bounds__(256) void cast_f32_bf16(const float* __restrict__ in,
                                                     __bf16* __restrict__ out, int n4) {
  int i = blockIdx.x * 256 + threadIdx.x;
  if (i >= n4) return;
  float4 f = ((const float4*)in)[i];
  union { __bf16 h[4]; uint2 u; } o;
  o.h[0] = (__bf16)f.x; o.h[1] = (__bf16)f.y; o.h[2] = (__bf16)f.z; o.h[3] = (__bf16)f.w;
  ((uint2*)out)[i] = o.u;
}

// ---------- K0b: tiled transpose: out[c*R + r] = (bf16) in[r*C + c] ---------
// 64x64 tiles via LDS (coalesced both sides). grid = (R/64)*(C/64).
__global__ __launch_bounds__(256) void transpose_cast(const float* __restrict__ in,
                                                      __bf16* __restrict__ out, int R, int C) {
  __shared__ float t[64][65];
  const int tilesR = R >> 6;
  const int tr = blockIdx.x % tilesR, tc = blockIdx.x / tilesR;
  const int tx = threadIdx.x & 63, ty = threadIdx.x >> 6;
  const int r0 = tr * 64, c0 = tc * 64;
#pragma unroll
  for (int p = 0; p < 16; p++) {
    int r = p * 4 + ty;
    t[r][tx] = in[(size_t)(r0 + r) * C + c0 + tx];
  }
  __syncthreads();
#pragma unroll
  for (int p = 0; p < 16; p++) {
    int c = p * 4 + ty;
    out[(size_t)(c0 + c) * R + r0 + tx] = (__bf16)t[tx][c];
  }
}

// ---- K0c: Wq_cast[r][k] = (bf16) Wqkv[r][k], k<768 (strided row cast) ------
__global__ __launch_bounds__(256) void wq_cast(const float* __restrict__ in,
                                               __bf16* __restrict__ out) {
  int o = blockIdx.x * 256 + threadIdx.x;   // o in [0, 768*768)
  int r = o / 768, c = o - r * 768;
  out[o] = (__bf16)in[r * 2304 + c];
}

// ---------------- K1: GEMM1 kv = Xb @ Wqkv[:,768:], 32x32x16 MFMA -----------
// A [32768,768] bf16 RM, B^T = WqkvT rows 768..2303 [1536,768] bf16 RM.
// 128x128 tile, BK=32, 4 waves of 64x64 (2x2 mfma 32x32x16).
// LDS k-chunk swizzle: stored_chunk = logical_chunk ^ ((row>>1)&3); staging
// permutes per-lane GLOBAL addresses (LDS dest is fixed base+lane*16).
__global__ __launch_bounds__(256) void gemm1_kv(const __bf16* __restrict__ A,
                                                const __bf16* __restrict__ B,
                                                __bf16* __restrict__ KTo,
                                                __bf16* __restrict__ VTo) {
  constexpr int LDA = 768, LDB = 768, KTOT = 768;
  __shared__ __bf16 sA[128 * 32];
  __shared__ __bf16 sB[128 * 32];
  const int tid = threadIdx.x;
  // XCD swizzle: all 12 nt for one mt land on the same XCD (A-tile L2 reuse)
  const int xcd = blockIdx.x & 7, g = blockIdx.x >> 3;
  const int mt = xcd * 32 + g / 12, nt = g % 12;
  const int lane = tid & 63, wv = tid >> 6;
  const int wr = (wv >> 1) * 64, wc = (wv & 1) * 64;
  const int l31 = lane & 31, l5 = lane >> 5;

  // staging: slot tid -> row tid>>2, stored chunk tid&3 -> swizzled global k
  const int srow = tid >> 2;
  const int sk = ((tid & 3) ^ ((srow >> 1) & 3)) * 8;
  const __bf16* gA = A + (size_t)(mt * 128 + srow) * LDA + sk;
  const __bf16* gB = B + (size_t)(nt * 128 + srow) * LDB + sk;

  // ds_read offsets (elements), loop-invariant
  const int arow = wr + l31, brow = wc + l31;
  const int asw = (arow >> 1) & 3, bsw = (brow >> 1) & 3;
  const int aoff  = arow * 32 + ((l5 ^ asw) * 8);          // ks=0
  const int aoff2 = arow * 32 + (((2 | l5) ^ asw) * 8);    // ks=16
  const int boff  = brow * 32 + ((l5 ^ bsw) * 8);
  const int boff2 = brow * 32 + (((2 | l5) ^ bsw) * 8);

  f16_t acc[2][2];
#pragma unroll
  for (int i = 0; i < 2; i++)
#pragma unroll
    for (int j = 0; j < 2; j++)
#pragma unroll
      for (int e = 0; e < 16; e++) acc[i][j][e] = 0.f;

  for (int k0 = 0; k0 < KTOT; k0 += 32) {
    gload16(gA, &sA[tid * 8]);
    gload16(gA + 64 * LDA, &sA[tid * 8 + 2048]);
    gload16(gB, &sB[tid * 8]);
    gload16(gB + 64 * LDB, &sB[tid * 8 + 2048]);
    gA += 32; gB += 32;
    __syncthreads();
    bf8_t a0 = *(const bf8_t*)&sA[aoff];
    bf8_t a1 = *(const bf8_t*)&sA[aoff + 1024];
    bf8_t b0 = *(const bf8_t*)&sB[boff];
    bf8_t b1 = *(const bf8_t*)&sB[boff + 1024];
    acc[0][0] = __builtin_amdgcn_mfma_f32_32x32x16_bf16(a0, b0, acc[0][0], 0, 0, 0);
    acc[0][1] = __builtin_amdgcn_mfma_f32_32x32x16_bf16(a0, b1, acc[0][1], 0, 0, 0);
    acc[1][0] = __builtin_amdgcn_mfma_f32_32x32x16_bf16(a1, b0, acc[1][0], 0, 0, 0);
    acc[1][1] = __builtin_amdgcn_mfma_f32_32x32x16_bf16(a1, b1, acc[1][1], 0, 0, 0);
    a0 = *(const bf8_t*)&sA[aoff2];
    a1 = *(const bf8_t*)&sA[aoff2 + 1024];
    b0 = *(const bf8_t*)&sB[boff2];
    b1 = *(const bf8_t*)&sB[boff2 + 1024];
    acc[0][0] = __builtin_amdgcn_mfma_f32_32x32x16_bf16(a0, b0, acc[0][0], 0, 0, 0);
    acc[0][1] = __builtin_amdgcn_mfma_f32_32x32x16_bf16(a0, b1, acc[0][1], 0, 0, 0);
    acc[1][0] = __builtin_amdgcn_mfma_f32_32x32x16_bf16(a1, b0, acc[1][0], 0, 0, 0);
    acc[1][1] = __builtin_amdgcn_mfma_f32_32x32x16_bf16(a1, b1, acc[1][1], 0, 0, 0);
    __syncthreads();
  }

  // epilogue: 32x32 C/D layout col = lane&31, row = (reg&3)+8*(reg>>2)+4*l5
  const int s = nt / 6;
  __bf16* T = (s == 0) ? KTo : VTo;
  const int row0 = mt * 128 + wr;
  const int bidx = row0 >> 12;          // 128-row tile never crosses batch
  const int n0 = (row0 & 4095) + 4 * l5;
  const int colw0 = (nt % 6) * 128 + wc;
#pragma unroll
  for (int j = 0; j < 2; j++) {
    int cw = colw0 + j * 32 + l31;
    int h = cw >> 6, d = cw & 63;
    __bf16* Tp = &T[((size_t)(bidx * 12 + h) * 64 + d) * 4096];
#pragma unroll
    for (int i = 0; i < 2; i++) {
      int nb = n0 + i * 32;
#pragma unroll
      for (int r2 = 0; r2 < 4; r2++) {
        union { __bf16 h4[4]; uint2 u; } pk;
#pragma unroll
        for (int r = 0; r < 4; r++) pk.h4[r] = (__bf16)acc[i][j][r2 * 4 + r];
        *(uint2*)&Tp[nb + 8 * r2] = pk.u;
      }
    }
  }
}

// ------ K3: row stats (max, 1/sumexp) per KT row; NO writeback --------------
__global__ __launch_bounds__(256) void stats_rows(const __bf16* __restrict__ KT,
                                                  float2* __restrict__ stats) {
  __shared__ float red[8];
  const __bf16* p = KT + (size_t)blockIdx.x * 4096;
  const int tid = threadIdx.x, lane = tid & 63, wv = tid >> 6;
  bf8_t x0 = *(const bf8_t*)&p[tid * 16];
  bf8_t x1 = *(const bf8_t*)&p[tid * 16 + 8];
  float v[16];
#pragma unroll
  for (int k = 0; k < 8; k++) { v[k] = (float)x0[k]; v[8 + k] = (float)x1[k]; }
  float m = v[0];
#pragma unroll
  for (int k = 1; k < 16; k++) m = fmaxf(m, v[k]);
  for (int o = 32; o; o >>= 1) m = fmaxf(m, __shfl_xor(m, o, 64));
  if (lane == 0) red[wv] = m;
  __syncthreads();
  m = fmaxf(fmaxf(red[0], red[1]), fmaxf(red[2], red[3]));
  float s = 0.f;
#pragma unroll
  for (int k = 0; k < 16; k++) s += __expf(v[k] - m);
  for (int o = 32; o; o >>= 1) s += __shfl_xor(s, o, 64);
  if (lane == 0) red[4 + wv] = s;
  __syncthreads();
  if (tid == 0) {
    float st = red[4] + red[5] + red[6] + red[7];
    stats[blockIdx.x] = make_float2(m, 1.0f / st);
  }
}

// --------- K4: ctx partials with inline exp. grid = 96*8 --------------------
// part[(bh*8+kc)][d][e] = sum_{n in slice} P[bh][d][n] * VT[bh][e][n],
//   P = exp(KT - m_row) * inv_row   (rounded to bf16 like before)
__global__ __launch_bounds__(256) void ctx_kernel(const __bf16* __restrict__ KT,
                                                  const __bf16* __restrict__ VT,
                                                  const float2* __restrict__ stats,
                                                  float* __restrict__ part) {
  const int bh = blockIdx.x >> 3, kc = blockIdx.x & 7;
  const int tid = threadIdx.x, lane = tid & 63, wv = tid >> 6;
  const int wr = (wv >> 1) * 32, wc = (wv & 1) * 32;
  const int lr = lane & 15, quad = lane >> 4;
  const __bf16* Ab = KT + (size_t)bh * 64 * 4096;
  const __bf16* Bb = VT + (size_t)bh * 64 * 4096;
  float2 st[2];
  st[0] = stats[bh * 64 + wr + lr];
  st[1] = stats[bh * 64 + wr + 16 + lr];
  const f4_t fz = {0.f, 0.f, 0.f, 0.f};
  f4_t acc[2][2] = {{fz, fz}, {fz, fz}};
  const int kbeg = kc * 512;
  for (int k0 = kbeg; k0 < kbeg + 512; k0 += 32) {
    bf8_t a[2], b[2];
#pragma unroll
    for (int i = 0; i < 2; i++) {
      bf8_t raw = *(const bf8_t*)&Ab[(size_t)(wr + i * 16 + lr) * 4096 + k0 + quad * 8];
#pragma unroll
      for (int e = 0; e < 8; e++)
        a[i][e] = (__bf16)(__expf((float)raw[e] - st[i].x) * st[i].y);
    }
#pragma unroll
    for (int j = 0; j < 2; j++)
      b[j] = *(const bf8_t*)&Bb[(size_t)(wc + j * 16 + lr) * 4096 + k0 + quad * 8];
#pragma unroll
    for (int i = 0; i < 2; i++)
#pragma unroll
      for (int j = 0; j < 2; j++)
        acc[i][j] = __builtin_amdgcn_mfma_f32_16x16x32_bf16(a[i], b[j], acc[i][j], 0, 0, 0);
  }
  float* po = part + (size_t)blockIdx.x * 4096;
#pragma unroll
  for (int i = 0; i < 2; i++)
#pragma unroll
    for (int j = 0; j < 2; j++)
#pragma unroll
      for (int r = 0; r < 4; r++)
        po[(wr + i * 16 + quad * 4 + r) * 64 + wc + j * 16 + lr] = acc[i][j][r];
}

// -------- K5: B2T[b][c][h*64+d] = sum_e ctx[bh][d][e] * Wproj[h*64+e][c] ----
__global__ __launch_bounds__(256) void wfused_kernel(const float* __restrict__ part,
                                                     const __bf16* __restrict__ WpT,
                                                     __bf16* __restrict__ B2T) {
  __shared__ __bf16 sctx[64 * 64];
  const int bh = blockIdx.x, cblk = blockIdx.y;
  const int b = bh / 12, h = bh % 12;
  const int tid = threadIdx.x;
  for (int i = tid; i < 4096; i += 256) {
    float s = 0.f;
#pragma unroll
    for (int kc = 0; kc < 8; kc++) s += part[(size_t)(bh * 8 + kc) * 4096 + i];
    sctx[i] = (__bf16)s;
  }
  __syncthreads();
  const int lane = tid & 63, wv = tid >> 6, lr = lane & 15, quad = lane >> 4;
  const int c0 = cblk * 192 + wv * 48;
  const f4_t fz = {0.f, 0.f, 0.f, 0.f};
  f4_t acc[3][4];
#pragma unroll
  for (int i = 0; i < 3; i++)
#pragma unroll
    for (int j = 0; j < 4; j++) acc[i][j] = fz;
#pragma unroll
  for (int k0 = 0; k0 < 64; k0 += 32) {
    bf8_t a[3], bq[4];
#pragma unroll
    for (int i = 0; i < 3; i++)
      a[i] = *(const bf8_t*)&WpT[(size_t)(c0 + i * 16 + lr) * 768 + h * 64 + k0 + quad * 8];
#pragma unroll
    for (int j = 0; j < 4; j++)
      bq[j] = *(const bf8_t*)&sctx[(j * 16 + lr) * 64 + k0 + quad * 8];
#pragma unroll
    for (int i = 0; i < 3; i++)
#pragma unroll
      for (int j = 0; j < 4; j++)
        acc[i][j] = __builtin_amdgcn_mfma_f32_16x16x32_bf16(a[i], bq[j], acc[i][j], 0, 0, 0);
  }
#pragma unroll
  for (int i = 0; i < 3; i++)
#pragma unroll
    for (int j = 0; j < 4; j++)
#pragma unroll
      for (int r = 0; r < 4; r++) {
        int c = c0 + i * 16 + quad * 4 + r;
        int d = j * 16 + lr;
        B2T[((size_t)b * 768 + c) * 768 + h * 64 + d] = (__bf16)acc[i][j][r];
      }
}

// ------ K5b: combine  Wcomb^T[b][c_out][c_in] = sum_k B2T[b][c_out][k]*Wq[c_in][k]
__global__ __launch_bounds__(256) void combine_kernel(const __bf16* __restrict__ B2Tall,
                                                      const __bf16* __restrict__ Wq,
                                                      __bf16* __restrict__ Wcomb) {
  constexpr int LD = 768, BK = 32, KTOT = 768;
  __shared__ __bf16 sA[64 * 32];
  __shared__ __bf16 sB[64 * 32];
  const int b = blockIdx.x / 144, rem = blockIdx.x % 144;
  const int mt = rem / 12, nt = rem % 12;
  const __bf16* A = B2Tall + (size_t)b * 768 * 768;
  const int tid = threadIdx.x, lane = tid & 63, wv = tid >> 6;
  const int wr = (wv >> 1) * 32, wc = (wv & 1) * 32;
  const int lr = lane & 15, quad = lane >> 4;

  const int e0 = tid * 8;
  const int srow = e0 >> 5, skk = e0 & 31;
  const __bf16* gA = A + (size_t)(mt * 64 + srow) * LD + skk;
  const __bf16* gB = Wq + (size_t)(nt * 64 + srow) * LD + skk;

  const f4_t fz = {0.f, 0.f, 0.f, 0.f};
  f4_t acc[2][2] = {{fz, fz}, {fz, fz}};

  for (int k0 = 0; k0 < KTOT; k0 += BK) {
    gload16(gA, &sA[e0]);
    gload16(gB, &sB[e0]);
    gA += BK; gB += BK;
    __syncthreads();
    bf8_t a[2], bq[2];
#pragma unroll
    for (int i = 0; i < 2; i++)
      a[i] = *(const bf8_t*)&sA[(wr + i * 16 + lr) * 32 + quad * 8];
#pragma unroll
    for (int j = 0; j < 2; j++)
      bq[j] = *(const bf8_t*)&sB[(wc + j * 16 + lr) * 32 + quad * 8];
#pragma unroll
    for (int i = 0; i < 2; i++)
#pragma unroll
      for (int j = 0; j < 2; j++)
        acc[i][j] = __builtin_amdgcn_mfma_f32_16x16x32_bf16(a[i], bq[j], acc[i][j], 0, 0, 0);
    __syncthreads();
  }
  __bf16* C = Wcomb + (size_t)b * 768 * 768;
  const int row0 = mt * 64 + wr, col0 = nt * 64 + wc;
#pragma unroll
  for (int i = 0; i < 2; i++)
#pragma unroll
    for (int j = 0; j < 2; j++)
#pragma unroll
      for (int r = 0; r < 4; r++)
        C[(size_t)(row0 + i * 16 + quad * 4 + r) * 768 + col0 + j * 16 + lr] =
            (__bf16)acc[i][j][r];
}

// ------------- K6: GEMM2 out = Xb @ Wcomb^T[b] + bproj, 32x32x16 ------------
__global__ __launch_bounds__(256) void gemm2_out(const __bf16* __restrict__ A,
                                                 const __bf16* __restrict__ Ball,
                                                 float* __restrict__ C,
                                                 const float* __restrict__ bias) {
  constexpr int LDA = 768, LDB = 768, KTOT = 768;
  __shared__ __bf16 sA[128 * 32];
  __shared__ __bf16 sB[128 * 32];
  const int tid = threadIdx.x;
  // XCD swizzle: each XCD owns one batch -> its Wcomb (1.2 MB) L2-resident
  const int xcd = blockIdx.x & 7, g = blockIdx.x >> 3;
  const int mt = xcd * 32 + g / 6, nt = g % 6;
  const __bf16* B = Ball + (size_t)(mt >> 5) * 768 * 768;
  const int lane = tid & 63, wv = tid >> 6;
  const int wr = (wv >> 1) * 64, wc = (wv & 1) * 64;
  const int l31 = lane & 31, l5 = lane >> 5;

  const int srow = tid >> 2;
  const int sk = ((tid & 3) ^ ((srow >> 1) & 3)) * 8;
  const __bf16* gA = A + (size_t)(mt * 128 + srow) * LDA + sk;
  const __bf16* gB = B + (size_t)(nt * 128 + srow) * LDB + sk;

  const int arow = wr + l31, brow = wc + l31;
  const int asw = (arow >> 1) & 3, bsw = (brow >> 1) & 3;
  const int aoff  = arow * 32 + ((l5 ^ asw) * 8);
  const int aoff2 = arow * 32 + (((2 | l5) ^ asw) * 8);
  const int boff  = brow * 32 + ((l5 ^ bsw) * 8);
  const int boff2 = brow * 32 + (((2 | l5) ^ bsw) * 8);

  f16_t acc[2][2];
#pragma unroll
  for (int i = 0; i < 2; i++)
#pragma unroll
    for (int j = 0; j < 2; j++)
#pragma unroll
      for (int e = 0; e < 16; e++) acc[i][j][e] = 0.f;

  for (int k0 = 0; k0 < KTOT; k0 += 32) {
    gload16(gA, &sA[tid * 8]);
    gload16(gA + 64 * LDA, &sA[tid * 8 + 2048]);
    gload16(gB, &sB[tid * 8]);
    gload16(gB + 64 * LDB, &sB[tid * 8 + 2048]);
    gA += 32; gB += 32;
    __syncthreads();
    bf8_t a0 = *(const bf8_t*)&sA[aoff];
    bf8_t a1 = *(const bf8_t*)&sA[aoff + 1024];
    bf8_t b0 = *(const bf8_t*)&sB[boff];
    bf8_t b1 = *(const bf8_t*)&sB[boff + 1024];
    acc[0][0] = __builtin_amdgcn_mfma_f32_32x32x16_bf16(a0, b0, acc[0][0], 0, 0, 0);
    acc[0][1] = __builtin_amdgcn_mfma_f32_32x32x16_bf16(a0, b1, acc[0][1], 0, 0, 0);
    acc[1][0] = __builtin_amdgcn_mfma_f32_32x32x16_bf16(a1, b0, acc[1][0], 0, 0, 0);
    acc[1][1] = __builtin_amdgcn_mfma_f32_32x32x16_bf16(a1, b1, acc[1][1], 0, 0, 0);
    a0 = *(const bf8_t*)&sA[aoff2];
    a1 = *(const bf8_t*)&sA[aoff2 + 1024];
    b0 = *(const bf8_t*)&sB[boff2];
    b1 = *(const bf8_t*)&sB[boff2 + 1024];
    acc[0][0] = __builtin_amdgcn_mfma_f32_32x32x16_bf16(a0, b0, acc[0][0], 0, 0, 0);
    acc[0][1] = __builtin_amdgcn_mfma_f32_32x32x16_bf16(a0, b1, acc[0][1], 0, 0, 0);
    acc[1][0] = __builtin_amdgcn_mfma_f32_32x32x16_bf16(a1, b0, acc[1][0], 0, 0, 0);
    acc[1][1] = __builtin_amdgcn_mfma_f32_32x32x16_bf16(a1, b1, acc[1][1], 0, 0, 0);
    __syncthreads();
  }

  const int row0 = mt * 128 + wr + 4 * l5;
  const int col0 = nt * 128 + wc;
#pragma unroll
  for (int j = 0; j < 2; j++) {
    int col = col0 + j * 32 + l31;
    float bv = bias[col];
#pragma unroll
    for (int i = 0; i < 2; i++)
#pragma unroll
      for (int r2 = 0; r2 < 4; r2++) {
        int rbase = row0 + i * 32 + 8 * r2;
#pragma unroll
        for (int r = 0; r < 4; r++)
          C[(size_t)(rbase + r) * 768 + col] = acc[i][j][r2 * 4 + r] + bv;
      }
  }
}

// ---------------------------------------------------------------------------
extern "C" void kernel_launch(void* const* d_in, const int* in_sizes, int n_in,
                              void* d_out, int out_size, void* d_ws, size_t ws_size,
                              hipStream_t stream) {
  const float* x = (const float*)d_in[0];      // [8,4096,768]
  const float* Wqkv = (const float*)d_in[1];   // [768,2304]
  const float* Wproj = (const float*)d_in[2];  // [768,768]
  const float* bproj = (const float*)d_in[3];  // [768]
  float* out = (float*)d_out;                  // [8,4096,768]

  char* ws = (char*)d_ws;
  __bf16* Xb    = (__bf16*)(ws + 0);            // 50,331,648
  __bf16* KT    = (__bf16*)(ws + 50331648);     // 50,331,648
  __bf16* VT    = (__bf16*)(ws + 100663296);    // 50,331,648
  __bf16* WqkvT = (__bf16*)(ws + 150994944);    //  3,538,944 (dead after gemm1)
  float2* stats = (float2*)(ws + 150994944);    //  49,152 (aliases dead WqkvT)
  __bf16* Wqc   = (__bf16*)(ws + 154533888);    //  1,179,648
  __bf16* WpT   = (__bf16*)(ws + 155713536);    //  1,179,648
  float*  part  = (float*)(ws + 156893184);     // 12,582,912
  __bf16* B2T   = (__bf16*)(ws + 169476096);    //  9,437,184
  __bf16* Wcomb = (__bf16*)(ws + 178913280);    //  9,437,184 -> end 188,350,464

  cast_f32_bf16<<<24576, 256, 0, stream>>>(x, Xb, 25165824 / 4);
  transpose_cast<<<12 * 36, 256, 0, stream>>>(Wqkv, WqkvT, 768, 2304);
  wq_cast<<<(768 * 768) / 256, 256, 0, stream>>>(Wqkv, Wqc);
  transpose_cast<<<12 * 12, 256, 0, stream>>>(Wproj, WpT, 768, 768);
  gemm1_kv<<<3072, 256, 0, stream>>>(Xb, WqkvT + 768 * 768, KT, VT);
  stats_rows<<<6144, 256, 0, stream>>>(KT, stats);
  ctx_kernel<<<96 * 8, 256, 0, stream>>>(KT, VT, stats, part);
  wfused_kernel<<<dim3(96, 4), 256, 0, stream>>>(part, WpT, B2T);
  combine_kernel<<<1152, 256, 0, stream>>>(B2T, Wqc, Wcomb);
  gemm2_out<<<1536, 256, 0, stream>>>(Xb, Wcomb, out, bproj);
}